// Round 2
// baseline (560.104 us; speedup 1.0000x reference)
//
#include <hip/hip_runtime.h>
#include <math.h>

// LearnableFlatPool: out[b,c,i,j] = max_{ki,kj} f[b,c,2i+ki,2j+kj] + h[c,ki,kj]
// h collapses to 3 per-channel constants: center=0, edge=-(1/t)^16, corner=-(2/t)^16.
//
// Layout: thread x-lane j (0..55) loads float4 covering input cols 4j..4j+3 of a
// row (56 lanes x 16B = 896B = exactly one full 224-float row, contiguous) and
// produces output cols 2j and 2j+1. Block (64,4) sweeps an 8-output-row strip so
// the shared input row between adjacent output rows hits L1/L2, not HBM.

namespace {
constexpr int Bn = 16, Cn = 128, Hn = 224, Wn = 224;
constexpr int Ho = 111, Wo = 111;
constexpr int ROWS_PER_BLOCK = 8;
}

__global__ __launch_bounds__(256) void lfp_kernel(const float* __restrict__ f,
                                                  const float* __restrict__ t,
                                                  float* __restrict__ out) {
    const int j  = threadIdx.x;           // 0..63, active 0..55
    const int bc = blockIdx.z;            // b*C + c
    const int c  = bc & (Cn - 1);

    // Per-channel h constants (block-uniform; compiler scalarizes).
    const float tc = t[c];
    const float xe = 1.0f / tc, xc = 2.0f / tc;
    float e2 = xe * xe, e4 = e2 * e2, e8 = e4 * e4;
    float c2 = xc * xc, c4 = c2 * c2, c8 = c4 * c4;
    const float hE = -(e8 * e8);          // edge taps
    const float hC = -(c8 * c8);          // corner taps

    if (j >= 56) return;
    const int col  = 4 * j;
    const int ecol = (col + 4 < Wn) ? col + 4 : Wn - 1;  // clamp lane 55 (its odd output is dropped)

    const float* fplane = f + (size_t)bc * Hn * Wn;
    float* oplane = out + (size_t)bc * Ho * Wo;

#pragma unroll
    for (int ii = 0; ii < 2; ++ii) {
        const int i = blockIdx.y * ROWS_PER_BLOCK + ii * 4 + threadIdx.y;
        if (i < Ho) {
            const float* base = fplane + (size_t)(2 * i) * Wn;
            float me = -INFINITY, mo = -INFINITY;
#pragma unroll
            for (int ki = 0; ki < 3; ++ki) {
                const float4 v = *(const float4*)(base + (size_t)ki * Wn + col);
                const float  e = base[(size_t)ki * Wn + ecol];
                const float hA = (ki == 1) ? hE : hC;     // kj = 0, 2
                const float hB = (ki == 1) ? 0.0f : hE;   // kj = 1
                me = fmaxf(me, fmaxf(fmaxf(v.x + hA, v.y + hB), v.z + hA));
                mo = fmaxf(mo, fmaxf(fmaxf(v.z + hA, v.w + hB), e + hA));
            }
            float* orow = oplane + (size_t)i * Wo;
            orow[2 * j] = me;
            if (2 * j + 1 < Wo) orow[2 * j + 1] = mo;
        }
    }
}

extern "C" void kernel_launch(void* const* d_in, const int* in_sizes, int n_in,
                              void* d_out, int out_size, void* d_ws, size_t ws_size,
                              hipStream_t stream) {
    const float* f = (const float*)d_in[0];
    const float* t = (const float*)d_in[1];
    float* out = (float*)d_out;

    dim3 block(64, 4, 1);
    dim3 grid(1, (Ho + ROWS_PER_BLOCK - 1) / ROWS_PER_BLOCK, Bn * Cn); // (1, 14, 2048)
    lfp_kernel<<<grid, block, 0, stream>>>(f, t, out);
}